// Round 7
// baseline (67.776 us; speedup 1.0000x reference)
//
#include <hip/hip_runtime.h>
#include <hip/hip_bf16.h>

#define BB 2
#define NN 1024
#define MM 1024
#define DD 256
#define HH 128
#define C2LE 2.8853900817779268f       // 2*log2(e)
#define NEG2LOG2E -2.8853900817779268f // -2*log2(e)

typedef float v2f __attribute__((ext_vector_type(2)));
typedef float v4f __attribute__((ext_vector_type(4)));

// ---- Kernel 1: e = exp2(C*(x@W + bias)).  A-side -> EaT[b][h][n] (transposed,
// each thread stores 8 contiguous n).  B-side -> Eb[b][m][h] (row-major).
__global__ __launch_bounds__(256) void proj_kernel(
    const float* __restrict__ query, const float* __restrict__ key,
    const float* __restrict__ Wa_w, const float* __restrict__ Wa_b,
    const float* __restrict__ Wb_w, const float* __restrict__ Wb_b,
    float* __restrict__ EaT, float* __restrict__ Eb) {
    __shared__ float rows[8][DD];     // 8KB
    __shared__ float partial[8][HH];  // 4KB
    const int tid = threadIdx.x;
    const int rb = blockIdx.x * 8;
    const bool isA = rb < BB * NN;
    const float* in = isA ? query : key;
    const float* W  = isA ? Wa_w : Wb_w;
    const float* bias = isA ? Wa_b : Wb_b;
    const int base = isA ? rb : rb - BB * NN;

    const float4* in4 = (const float4*)(in + (size_t)base * DD);
    float4* rows4 = (float4*)rows;
    rows4[tid] = in4[tid];
    rows4[tid + 256] = in4[tid + 256];
    __syncthreads();

    const int h = tid & 127, half = tid >> 7;
    const int d0 = half * 128;
    float acc[8] = {};
    for (int d = d0; d < d0 + 128; d += 4) {
        const float w0 = W[(d + 0) * HH + h];
        const float w1 = W[(d + 1) * HH + h];
        const float w2 = W[(d + 2) * HH + h];
        const float w3 = W[(d + 3) * HH + h];
#pragma unroll
        for (int r = 0; r < 8; ++r) {
            const float4 rv = *(const float4*)&rows[r][d];
            acc[r] = fmaf(rv.x, w0, fmaf(rv.y, w1, fmaf(rv.z, w2, fmaf(rv.w, w3, acc[r]))));
        }
    }
    if (half) {
#pragma unroll
        for (int r = 0; r < 8; ++r) partial[r][h] = acc[r];
    }
    __syncthreads();
    if (!half) {
        const float bv = bias[h];
        float ev[8];
#pragma unroll
        for (int r = 0; r < 8; ++r)
            ev[r] = __builtin_amdgcn_exp2f(C2LE * (acc[r] + partial[r][h] + bv));
        if (isA) {
            const int bq = base >> 10, nb = base & (NN - 1);
            float* dst = EaT + ((size_t)(bq * HH + h)) * NN + nb;
            *(float4*)dst = *(float4*)&ev[0];
            *(float4*)(dst + 4) = *(float4*)&ev[4];
        } else {
#pragma unroll
            for (int r = 0; r < 8; ++r)
                Eb[(size_t)(base + r) * HH + h] = ev[r];
        }
    }
}

// ---- Kernel 2: P[b,n,m] = exp( -2 * sum_h v_h / (Ea*Eb + 1) )  (unnorm).
// a,w come from the SCALAR pipe (uniform s_loads); only b uses LDS.
// 4 h-terms share one rcp; packed over n-pairs (v2f).
__global__ __launch_bounds__(256) void scores_kernel(
    const float* __restrict__ EaT, const float* __restrict__ Eb,
    const float* __restrict__ v_w, float* __restrict__ P) {
    __shared__ float b_s[64 * HH];  // 32KB, XOR-swizzled rows
    const int tid = threadIdx.x;
    const int m0 = blockIdx.x * 64, n0 = blockIdx.y * 32, b = blockIdx.z;

    for (int i = tid; i < 64 * 32; i += 256) {
        const int r = i >> 5, h4 = i & 31;
        *(float4*)&b_s[r * HH + ((h4 ^ (r & 7)) << 2)] =
            *(const float4*)&Eb[((size_t)(b * MM + m0 + r)) * HH + h4 * 4];
    }
    __syncthreads();

    const int ml = tid & 63;
    const int ng = __builtin_amdgcn_readfirstlane(threadIdx.x >> 6);
    const int mlx = ml & 7;
    const float* brow = &b_s[ml * HH];
    const float* aT = EaT + (size_t)b * HH * NN + (n0 + ng * 8);  // uniform base
    v2f acc[4] = {};
    for (int h4 = 0; h4 < 32; ++h4) {
        const float4 b4 = *(const float4*)&brow[(h4 ^ mlx) << 2];  // per-lane LDS
        const float4 w4 = *(const float4*)&v_w[h4 * 4];            // uniform s_load
        const float* a0p = aT + (size_t)(h4 * 4 + 0) * NN;
        const float* a1p = aT + (size_t)(h4 * 4 + 1) * NN;
        const float* a2p = aT + (size_t)(h4 * 4 + 2) * NN;
        const float* a3p = aT + (size_t)(h4 * 4 + 3) * NN;
#pragma unroll
        for (int np = 0; np < 4; ++np) {
            const v2f a0 = *(const v2f*)&a0p[np * 2];  // uniform s_load pairs
            const v2f a1 = *(const v2f*)&a1p[np * 2];
            const v2f a2 = *(const v2f*)&a2p[np * 2];
            const v2f a3 = *(const v2f*)&a3p[np * 2];
            const v2f u0 = a0 * b4.x + 1.0f;
            const v2f u1 = a1 * b4.y + 1.0f;
            const v2f u2 = a2 * b4.z + 1.0f;
            const v2f u3 = a3 * b4.w + 1.0f;
            const v2f p01 = u0 * u1, p23 = u2 * u3;
            const v2f An = w4.x * u1 + w4.y * u0;
            const v2f Bn = w4.z * u3 + w4.w * u2;
            const v2f num = An * p23 + Bn * p01;
            const v2f Pp = p01 * p23;
            v2f r2;
            r2.x = __builtin_amdgcn_rcpf(Pp.x);
            r2.y = __builtin_amdgcn_rcpf(Pp.y);
            acc[np] = num * r2 + acc[np];
        }
    }

    const size_t rowbase = (size_t)b * NN * MM + (size_t)n0 * MM + m0 + ml;
#pragma unroll
    for (int np = 0; np < 4; ++np) {
        P[rowbase + (size_t)(ng * 8 + np * 2 + 0) * MM] =
            __builtin_amdgcn_exp2f(acc[np].x * NEG2LOG2E);
        P[rowbase + (size_t)(ng * 8 + np * 2 + 1) * MM] =
            __builtin_amdgcn_exp2f(acc[np].y * NEG2LOG2E);
    }
}

// ---- Kernel 3: PV over an m-slice, NO LDS. Wave owns 8 rows; p values are
// wave-uniform s_loads; k float4-loads with 4-deep register pipeline.
template <int NQ>
__global__ __launch_bounds__(512) void attend_kernel(
    const float* __restrict__ P, const float* __restrict__ key,
    float* __restrict__ partial, float* __restrict__ psums) {
    constexpr int MQ = MM / NQ;
    const int tid = threadIdx.x;
    const int wave = __builtin_amdgcn_readfirstlane(threadIdx.x >> 6);
    const int lane = tid & 63;
    const int n0 = blockIdx.x * 64;
    const int mq = blockIdx.y, b = blockIdx.z;
    const int m0 = mq * MQ;
    const int r0 = n0 + wave * 8;

    const float* pP = P + ((size_t)b * NN + r0) * MM + m0;

    // row sums: lane-parallel vector pass + shuffle reduce
#pragma unroll
    for (int i = 0; i < 8; ++i) {
        float s = 0.f;
#pragma unroll
        for (int c = 0; c < MQ / 128; ++c) {
            const float2 v = *(const float2*)&pP[(size_t)i * MM + c * 128 + lane * 2];
            s += v.x + v.y;
        }
#pragma unroll
        for (int o = 32; o > 0; o >>= 1) s += __shfl_xor(s, o);
        if (lane == 0) psums[((size_t)mq * BB + b) * NN + r0 + i] = s;
    }

    const float* kb = key + ((size_t)b * MM + m0) * DD + lane * 4;
    v4f acc[8] = {};
    v4f kc0 = *(const v4f*)&kb[0 * DD];
    v4f kc1 = *(const v4f*)&kb[1 * DD];
    v4f kc2 = *(const v4f*)&kb[2 * DD];
    v4f kc3 = *(const v4f*)&kb[3 * DD];

#define PV4(mm, K0, K1, K2, K3)                           \
    {                                                     \
        _Pragma("unroll")                                 \
        for (int i = 0; i < 8; ++i) {                     \
            const float* pr = &pP[(size_t)i * MM + (mm)]; \
            acc[i] = K0 * pr[0] + acc[i];                 \
            acc[i] = K1 * pr[1] + acc[i];                 \
            acc[i] = K2 * pr[2] + acc[i];                 \
            acc[i] = K3 * pr[3] + acc[i];                 \
        }                                                 \
    }

    int m = 0;
    for (; m < MQ - 4; m += 4) {
        const v4f kn0 = *(const v4f*)&kb[(size_t)(m + 4) * DD];
        const v4f kn1 = *(const v4f*)&kb[(size_t)(m + 5) * DD];
        const v4f kn2 = *(const v4f*)&kb[(size_t)(m + 6) * DD];
        const v4f kn3 = *(const v4f*)&kb[(size_t)(m + 7) * DD];
        PV4(m, kc0, kc1, kc2, kc3)
        kc0 = kn0; kc1 = kn1; kc2 = kn2; kc3 = kn3;
    }
    PV4(m, kc0, kc1, kc2, kc3)
#undef PV4

    const size_t base = (((size_t)mq * BB + b) * NN + r0) * DD + lane * 4;
#pragma unroll
    for (int i = 0; i < 8; ++i)
        *(v4f*)&partial[base + (size_t)i * DD] = acc[i];
}

// ---- Kernel 4: out[b,n,d] = sum_q partial[q][b,n,d] / sum_q psums[q][b,n]
template <int NQ>
__global__ __launch_bounds__(256) void combine_kernel(
    const float* __restrict__ partial, const float* __restrict__ psums,
    float* __restrict__ out) {
    const int n = blockIdx.x, b = blockIdx.y, d = threadIdx.x;
    float s = 0.f, a = 0.f;
#pragma unroll
    for (int q = 0; q < NQ; ++q) {
        s += psums[((size_t)q * BB + b) * NN + n];
        a += partial[(((size_t)q * BB + b) * NN + n) * DD + d];
    }
    out[((size_t)b * NN + n) * DD + d] = a * __builtin_amdgcn_rcpf(s);
}

extern "C" void kernel_launch(void* const* d_in, const int* in_sizes, int n_in,
                              void* d_out, int out_size, void* d_ws, size_t ws_size,
                              hipStream_t stream) {
    const float* query = (const float*)d_in[0];
    const float* key   = (const float*)d_in[1];
    const float* Wa_w  = (const float*)d_in[2];
    const float* Wa_b  = (const float*)d_in[3];
    const float* Wb_w  = (const float*)d_in[4];
    const float* Wb_b  = (const float*)d_in[5];
    const float* v_w   = (const float*)d_in[6];
    float* out = (float*)d_out;

    float* ws = (float*)d_ws;
    float* EaT = ws;                             // B*H*N
    float* Eb  = EaT + BB * NN * HH;             // B*M*H
    float* P   = Eb + BB * MM * HH;              // B*N*M
    float* partial = P + (size_t)BB * NN * MM;   // NQ*B*N*D
    const size_t base_f =
        (size_t)(BB * NN * HH) + BB * MM * HH + (size_t)BB * NN * MM;
    const size_t need8 =
        (base_f + (size_t)8 * BB * NN * DD + (size_t)8 * BB * NN + 2048) * sizeof(float);

    proj_kernel<<<dim3((BB * NN + BB * MM) / 8), dim3(256), 0, stream>>>(
        query, key, Wa_w, Wa_b, Wb_w, Wb_b, EaT, Eb);
    scores_kernel<<<dim3(MM / 64, NN / 32, BB), dim3(256), 0, stream>>>(
        EaT, Eb, v_w, P);
    if (ws_size >= need8) {
        float* psums = partial + (size_t)8 * BB * NN * DD;
        attend_kernel<8><<<dim3(NN / 64, 8, BB), dim3(512), 0, stream>>>(
            P, key, partial, psums);
        combine_kernel<8><<<dim3(NN, BB), dim3(256), 0, stream>>>(
            partial, psums, out);
    } else {
        float* psums = partial + (size_t)4 * BB * NN * DD;
        attend_kernel<4><<<dim3(NN / 64, 4, BB), dim3(512), 0, stream>>>(
            P, key, partial, psums);
        combine_kernel<4><<<dim3(NN, BB), dim3(256), 0, stream>>>(
            partial, psums, out);
    }
}